// Round 1
// baseline (1673.705 us; speedup 1.0000x reference)
//
#include <hip/hip_runtime.h>
#include <cstdint>

// ============================================================================
// RBM_BB block Gibbs, bit-exact (recipe frozen, R3/R5/R6/R7-verified):
//   keys   : partitionable threefry; fold-like split key_i = threefry(parent,0,i)
//   bits   : w0 ^ w1 of threefry(key, 0, flat_index); u = (bits>>9|1.0f)-1
//   sample : u < p
//   sigmoid: 1/(1+cephes_expf(-pre)), noFMA Horner, trailing max(res,x)
//   dot    : f32 sequential ascending-k, folded at kc=320 panel boundaries
// R12 perf: 128x128 tile, 8m x 8n per-thread register blocking (was 64x128,
// 4x8). LDS bytes per FMA-lane drop 1.5 -> 1.0 (both A and B LDS reads are
// now information-minimal), cutting CU LDS-read demand from ~192 B/cyc
// (over the ~112 B/cyc ceiling -> LDS-feed bound) to ~128 B/cyc.
// global_load_lds staging retained (linear LDS, 16B/lane). Per-output
// k-chain (c outer asc, cc inner asc) and fold order unchanged -> bit-exact.
// ============================================================================

#define TF_ROT(x, r) (((x) << (r)) | ((x) >> (32 - (r))))

__host__ __device__ __forceinline__ void threefry2x32(
    uint32_t k0, uint32_t k1, uint32_t x0, uint32_t x1,
    uint32_t &o0, uint32_t &o1) {
  const uint32_t ks2 = k0 ^ k1 ^ 0x1BD11BDAu;
  x0 += k0; x1 += k1;
#define TF_R(r) { x0 += x1; x1 = TF_ROT(x1, r); x1 ^= x0; }
  TF_R(13) TF_R(15) TF_R(26) TF_R(6)
  x0 += k1; x1 += ks2 + 1u;
  TF_R(17) TF_R(29) TF_R(16) TF_R(24)
  x0 += ks2; x1 += k0 + 2u;
  TF_R(13) TF_R(15) TF_R(26) TF_R(6)
  x0 += k0; x1 += k1 + 3u;
  TF_R(17) TF_R(29) TF_R(16) TF_R(24)
  x0 += k1; x1 += ks2 + 4u;
  TF_R(13) TF_R(15) TF_R(26) TF_R(6)
  x0 += ks2; x1 += k0 + 5u;
#undef TF_R
  o0 = x0; o1 = x1;
}

// Cephes expf, noFMA (verified in-chain).
__device__ __forceinline__ float cephes_expf(float xin) {
  float xc = fminf(xin, 88.3762626647950f);
  xc = fmaxf(xc, -88.3762626647949f);
  float fx = floorf(xc * 1.44269504088896341f + 0.5f);
  float tmp = 0.693359375f * fx;
  float z2  = -2.12194440e-4f * fx;
  float x = xc - tmp;
  x = x - z2;
  float z = x * x;
  float y = 1.9875691500E-4f * x + 1.3981999507E-3f;
  y = y * x + 8.3334519073E-3f;
  y = y * x + 4.1665795894E-2f;
  y = y * x + 1.6666665459E-1f;
  y = y * x + 5.0000001201E-1f;
  y = y * z + x;
  y = 1.0f + y;
  int n = (int)fx;
  float p2n = __uint_as_float((uint32_t)(n + 127) << 23);
  return fmaxf(y * p2n, xin);
}

__device__ __forceinline__ float sample_val(
    float tot, float bias, long b, int ng, int N_total,
    uint32_t k0, uint32_t k1) {
  float pre = tot + bias;
  float p   = 1.0f / (1.0f + cephes_expf(-pre));
  uint32_t flat = (uint32_t)(b * N_total + ng);
  uint32_t w0, w1;
  threefry2x32(k0, k1, 0u, flat, w0, w1);
  uint32_t bits = w0 ^ w1;
  float u = __uint_as_float((bits >> 9) | 0x3f800000u) - 1.0f;
  return (u < p) ? 1.0f : 0.0f;
}

// async global->LDS, 16B per lane; LDS dest = uniform base + lane*16.
__device__ __forceinline__ void gl2lds16(const float* g, float* l) {
  __builtin_amdgcn_global_load_lds(
      (const __attribute__((address_space(1))) void*)g,
      (__attribute__((address_space(3))) void*)l, 16, 0, 0);
}

// ----------------------------------------------------------------------------
// Main GEMM, 128x128 tile, BK=32, 256 threads, 8m x 8n per thread.
// A [Mtot,lda] row-major (k-contig); Bkm [K,ldb] k-major (n-contig rows).
// Thread (tx=t&15, ty=t>>4): rows m = ty+16*i (i=0..7), cols n = 4*tx+64*jq+e.
// SAMPLE=1: full K (single panel, K<=320 use only), fused sigmoid+threefry.
// SAMPLE=0: split-K partial over panel [z*320, min(K, z*320+320)) -> partials.
// Per-output chain: k = 32*tk + 4*c + cc, c outer asc, cc inner asc (exact).
// ----------------------------------------------------------------------------
template <bool SAMPLE>
__global__ __launch_bounds__(256, 4) void gemm_tile128(
    const float* __restrict__ A,     // [Mtot, lda]
    const float* __restrict__ Bkm,   // [K, ldb] k-major
    const float* __restrict__ bias,  // [N_total] (SAMPLE only)
    float* __restrict__ out,
    int lda, int ldb, int N_total, int K, int Mtot,
    uint32_t k0, uint32_t k1)
{
  __shared__ float As[128 * 32];    // [m][k] unpadded (lds-dma linear layout)
  __shared__ float Bs[32 * 128];    // [k][n] unpadded
  const int t  = threadIdx.x;
  const int tx = t & 15;
  const int ty = t >> 4;
  const int w  = t >> 6;            // wave id
  const int bm = blockIdx.x;
  const int j0 = blockIdx.y << 7;

  int kb, ke;
  float* outp = out;
  if (SAMPLE) { kb = 0; ke = K; }
  else {
    const int z = blockIdx.z;
    kb = z * 320;
    ke = min(K, kb + 320);
    outp = out + (size_t)z * Mtot * 128;
  }

  float cur[8][8];
#pragma unroll
  for (int i = 0; i < 8; ++i)
#pragma unroll
    for (int j = 0; j < 8; ++j) cur[i][j] = 0.0f;

  const long arow = (long)bm * 128 * lda;
  const int nt = (ke - kb) >> 5;    // k-tiles in this block's range

  // Per-thread staging source pointers (advance 32 cols / 32 rows per tile).
  // A tile: 1024 f4 slots, 4 rounds; slot = r*256+t; m = 32r + (t>>3), c = t&7.
  // B tile: 1024 f4 slots, 4 rounds; slot = r*256+t; kk = 8r + (t>>5), nc = t&31.
  const long aStepR = (long)32 * lda;   // A rows advance per round
  const long bStepR = (long)8  * ldb;   // B rows advance per round
  const float* aG = A + arow + (long)(t >> 3) * lda + 4 * (t & 7) + kb;
  const float* bG = Bkm + (long)(t >> 5) * ldb + j0 + 4 * (t & 31) + (long)kb * ldb;
  const long bStepT = (long)32 * ldb;   // B advance per k-tile

  const float* aP = As + ty * 32;
  const float* bP = Bs + 4 * tx;

  for (int tk = 0; tk < nt; ++tk) {
    __syncthreads();   // protect LDS reuse (prev tile's reads done)
#pragma unroll
    for (int r = 0; r < 4; ++r)
      gl2lds16(aG + r * aStepR, As + (r * 256 + w * 64) * 4);
#pragma unroll
    for (int r = 0; r < 4; ++r)
      gl2lds16(bG + r * bStepR, Bs + (r * 256 + w * 64) * 4);
    __syncthreads();   // vmcnt(0) drain: staged data visible

    // ---- compute: k ascending 4c+cc per output; B regs live across i ----
#pragma unroll
    for (int c = 0; c < 8; ++c) {
      float4 bq[4][2];
#pragma unroll
      for (int cc = 0; cc < 4; ++cc) {
        const float* brow = bP + (4 * c + cc) * 128;
        bq[cc][0] = *(const float4*)(brow);
        bq[cc][1] = *(const float4*)(brow + 64);
      }
#pragma unroll
      for (int i = 0; i < 8; ++i) {
        const float4 av = *(const float4*)(aP + i * 16 * 32 + 4 * c);
#pragma unroll
        for (int cc = 0; cc < 4; ++cc) {
          const float a = ((const float*)&av)[cc];
          cur[i][0] = __fmaf_rn(a, bq[cc][0].x, cur[i][0]);
          cur[i][1] = __fmaf_rn(a, bq[cc][0].y, cur[i][1]);
          cur[i][2] = __fmaf_rn(a, bq[cc][0].z, cur[i][2]);
          cur[i][3] = __fmaf_rn(a, bq[cc][0].w, cur[i][3]);
          cur[i][4] = __fmaf_rn(a, bq[cc][1].x, cur[i][4]);
          cur[i][5] = __fmaf_rn(a, bq[cc][1].y, cur[i][5]);
          cur[i][6] = __fmaf_rn(a, bq[cc][1].z, cur[i][6]);
          cur[i][7] = __fmaf_rn(a, bq[cc][1].w, cur[i][7]);
        }
      }
    }
    aG += 32;
    bG += bStepT;
  }

  // ---- epilogue: per (i,jq), 4 consecutive cols -> one float4 store ----
#pragma unroll
  for (int i = 0; i < 8; ++i) {
    const int m = ty + 16 * i;
    const long b = (long)bm * 128 + m;
#pragma unroll
    for (int jq = 0; jq < 2; ++jq) {
      const int n0 = 4 * tx + 64 * jq;
      float4 o;
      if (SAMPLE) {
        const int ng = j0 + n0;
        o.x = sample_val(cur[i][4 * jq + 0], bias[ng],     b, ng,     N_total, k0, k1);
        o.y = sample_val(cur[i][4 * jq + 1], bias[ng + 1], b, ng + 1, N_total, k0, k1);
        o.z = sample_val(cur[i][4 * jq + 2], bias[ng + 2], b, ng + 2, N_total, k0, k1);
        o.w = sample_val(cur[i][4 * jq + 3], bias[ng + 3], b, ng + 3, N_total, k0, k1);
        *(float4*)(outp + b * N_total + ng) = o;
      } else {
        o.x = cur[i][4 * jq + 0]; o.y = cur[i][4 * jq + 1];
        o.z = cur[i][4 * jq + 2]; o.w = cur[i][4 * jq + 3];
        *(float4*)(outp + b * 128 + n0) = o;   // j0==0, N_total==128
      }
    }
  }
}

// ----------------------------------------------------------------------------
// Fallback (no-workspace path only): previous 64x128 kernel, SAMPLE over full
// K with in-kernel panel folds (tiles_per_panel=10). Kept verbatim for the
// ws-short case; not used when split-K workspace is available.
// ----------------------------------------------------------------------------
__global__ __launch_bounds__(256, 5) void gemm_fb(
    const float* __restrict__ A,     // [Mtot, lda]
    const float* __restrict__ Bkm,   // [K, ldb] k-major
    const float* __restrict__ bias,  // [N_total]
    float* __restrict__ out,
    int lda, int ldb, int N_total, int K, int tiles_per_panel, int Mtot,
    uint32_t k0, uint32_t k1)
{
  __shared__ float As[64 * 32];
  __shared__ float Bs[32 * 128];
  const int t  = threadIdx.x;
  const int tx = t & 15;
  const int ty = t >> 4;
  const int w  = t >> 6;
  const int bm = blockIdx.x;
  const int j0 = blockIdx.y << 7;

  const int kb = 0, ke = K;

  float cur[4][8];
  float tot[4][8];
#pragma unroll
  for (int i = 0; i < 4; ++i)
#pragma unroll
    for (int j = 0; j < 8; ++j) { cur[i][j] = 0.0f; tot[i][j] = 0.0f; }

  const long arow = (long)bm * 64 * lda;
  const int t0 = kb >> 5, t1 = ke >> 5;

  const float* aP = As + ty * 32;
  const float* bP = Bs + 4 * tx;

  for (int tki = t0; tki < t1; ++tki) {
    const int kc = tki << 5;
    __syncthreads();
#pragma unroll
    for (int r = 0; r < 2; ++r) {
      int slot = r * 256 + t;
      int m = slot >> 3, c = slot & 7;
      gl2lds16(A + arow + (long)m * lda + kc + 4 * c,
               As + (r * 256 + w * 64) * 4);
    }
#pragma unroll
    for (int r = 0; r < 4; ++r) {
      int slot = r * 256 + t;
      int kk = slot >> 5, nc = slot & 31;
      gl2lds16(Bkm + (long)(kc + kk) * ldb + j0 + 4 * nc,
               Bs + (r * 256 + w * 64) * 4);
    }
    __syncthreads();

#pragma unroll
    for (int c = 0; c < 8; ++c) {
      float4 av[4];
#pragma unroll
      for (int i = 0; i < 4; ++i)
        av[i] = *(const float4*)(aP + i * 16 * 32 + 4 * c);
#pragma unroll
      for (int cc = 0; cc < 4; ++cc) {
        const float* brow = bP + (4 * c + cc) * 128;
        float4 b0 = *(const float4*)(brow);
        float4 b1 = *(const float4*)(brow + 64);
#pragma unroll
        for (int i = 0; i < 4; ++i) {
          const float a = ((const float*)&av[i])[cc];
          cur[i][0] = __fmaf_rn(a, b0.x, cur[i][0]);
          cur[i][1] = __fmaf_rn(a, b0.y, cur[i][1]);
          cur[i][2] = __fmaf_rn(a, b0.z, cur[i][2]);
          cur[i][3] = __fmaf_rn(a, b0.w, cur[i][3]);
          cur[i][4] = __fmaf_rn(a, b1.x, cur[i][4]);
          cur[i][5] = __fmaf_rn(a, b1.y, cur[i][5]);
          cur[i][6] = __fmaf_rn(a, b1.z, cur[i][6]);
          cur[i][7] = __fmaf_rn(a, b1.w, cur[i][7]);
        }
      }
    }

    if (((tki - t0 + 1) % tiles_per_panel == 0) || (tki == t1 - 1)) {
#pragma unroll
      for (int i = 0; i < 4; ++i)
#pragma unroll
        for (int j = 0; j < 8; ++j) { tot[i][j] += cur[i][j]; cur[i][j] = 0.0f; }
    }
  }

#pragma unroll
  for (int i = 0; i < 4; ++i) {
    const int m = ty + 16 * i;
    const long b = (long)bm * 64 + m;
#pragma unroll
    for (int jq = 0; jq < 2; ++jq) {
      const int n0 = 4 * tx + 64 * jq;
      const int ng = j0 + n0;
      float4 o;
      o.x = sample_val(tot[i][4 * jq + 0], bias[ng],     b, ng,     N_total, k0, k1);
      o.y = sample_val(tot[i][4 * jq + 1], bias[ng + 1], b, ng + 1, N_total, k0, k1);
      o.z = sample_val(tot[i][4 * jq + 2], bias[ng + 2], b, ng + 2, N_total, k0, k1);
      o.w = sample_val(tot[i][4 * jq + 3], bias[ng + 3], b, ng + 3, N_total, k0, k1);
      *(float4*)(out + b * N_total + ng) = o;
    }
  }
}

// Fold 4 panel partials in exact order, then bias+sigmoid+sample.
__global__ __launch_bounds__(256) void combine_sample(
    const float* __restrict__ partials,  // [4][Mtot*128]
    const float* __restrict__ bias,      // [128]
    float* __restrict__ out,             // [Mtot*128] binary f32
    int Mtot, uint32_t k0, uint32_t k1)
{
  const long idx = (long)blockIdx.x * 256 + threadIdx.x;
  const long S = (long)Mtot * 128;
  float p0 = partials[idx];
  float p1 = partials[S + idx];
  float p2 = partials[2 * S + idx];
  float p3 = partials[3 * S + idx];
  float tot = ((p0 + p1) + p2) + p3;          // Eigen fold order, exact
  float pre = tot + bias[(int)(idx & 127)];
  float p   = 1.0f / (1.0f + cephes_expf(-pre));
  uint32_t w0, w1;
  threefry2x32(k0, k1, 0u, (uint32_t)idx, w0, w1);
  uint32_t bits = w0 ^ w1;
  float u = __uint_as_float((bits >> 9) | 0x3f800000u) - 1.0f;
  out[idx] = (u < p) ? 1.0f : 0.0f;
}

__global__ void transpose_W(const float* __restrict__ W, float* __restrict__ Wt) {
  __shared__ float tile[32][33];
  int bx = blockIdx.x, by = blockIdx.y;
  int x = threadIdx.x, y = threadIdx.y;
  tile[y][x] = W[(by * 32 + y) * 1024 + bx * 32 + x];
  __syncthreads();
  Wt[(bx * 32 + y) * 128 + by * 32 + x] = tile[x][y];
}

extern "C" void kernel_launch(void* const* d_in, const int* in_sizes, int n_in,
                              void* d_out, int out_size, void* d_ws, size_t ws_size,
                              hipStream_t stream) {
  const float* v0 = (const float*)d_in[0];   // [B,1024]
  const float* W  = (const float*)d_in[1];   // [128,1024]
  const float* bb = (const float*)d_in[2];   // [1024]
  const float* cb = (const float*)d_in[3];   // [128]
  const int B = in_sizes[0] / 1024;          // 32768

  float* out    = (float*)d_out;
  float* out_v  = out;                        // v_given_h   [B,1024]
  float* out_h1 = out + (size_t)B * 1024;     // h_given_v   [B,128]
  float* out_h2 = out_h1 + (size_t)B * 128;   // h_given_v_0 [B,128]

  float* Wt       = (float*)d_ws;                       // [1024,128] k-major for h-GEMM
  float* h_ws     = Wt + 1024 * 128;                    // [B,128]
  float* partials = h_ws + (size_t)B * 128;             // [4][B,128]
  const size_t need = (size_t)(1024 * 128 + (size_t)B * 128 * 5) * 4;
  const bool use_split = ws_size >= need;

  // partitionable keys: seed 42, fold-like split
  uint32_t kt[5][2], kv[5][2], kh[5][2];
  for (uint32_t i = 0; i < 5; ++i) threefry2x32(0u, 42u, 0u, i, kt[i][0], kt[i][1]);
  for (int t = 1; t <= 4; ++t) {
    threefry2x32(kt[t][0], kt[t][1], 0u, 0u, kv[t][0], kv[t][1]);
    threefry2x32(kt[t][0], kt[t][1], 0u, 1u, kh[t][0], kh[t][1]);
  }

  transpose_W<<<dim3(32, 4), dim3(32, 32), 0, stream>>>(W, Wt);

  const int MB = B / 128;    // 256 row-blocks (128-row tiles)

  // h-step: hdst = bernoulli(key, sigmoid(W vin + c)); Bkm = Wt (ldb=128)
  auto h_step = [&](const float* vin, float* hdst, uint32_t hk0, uint32_t hk1) {
    if (use_split) {
      gemm_tile128<false><<<dim3(MB, 1, 4), 256, 0, stream>>>(
          vin, Wt, nullptr, partials, 1024, 128, 128, 1024, B, 0u, 0u);
      combine_sample<<<dim3(B * 128 / 256), 256, 0, stream>>>(
          partials, cb, hdst, B, hk0, hk1);
    } else {
      gemm_fb<<<dim3(B / 64, 1, 1), 256, 0, stream>>>(
          vin, Wt, cb, hdst, 1024, 128, 128, 1024, 10, B, hk0, hk1);
    }
  };

  // h0 = bernoulli(kt[0], sigmoid(W v0 + c))
  h_step(v0, out_h2, kt[0][0], kt[0][1]);

  const float* h = out_h2;
  for (int t = 1; t <= 4; ++t) {
    // v_t = bernoulli(kv[t], sigmoid(W^T h + b)) — K=128 (<320, single panel)
    gemm_tile128<true><<<dim3(MB, 8, 1), 256, 0, stream>>>(
        h, W, bb, out_v, 128, 1024, 1024, 128, B, kv[t][0], kv[t][1]);
    // h_t = bernoulli(kh[t], sigmoid(W v_t + c))
    float* hdst = (t == 4) ? out_h1 : h_ws;
    h_step(out_v, hdst, kh[t][0], kh[t][1]);
    h = hdst;
  }
}

// Round 2
// 1404.394 us; speedup vs baseline: 1.1918x; 1.1918x over previous
//
#include <hip/hip_runtime.h>
#include <cstdint>

// ============================================================================
// RBM_BB block Gibbs, bit-exact (recipe frozen, R3/R5/R6/R7-verified):
//   keys   : partitionable threefry; fold-like split key_i = threefry(parent,0,i)
//   bits   : w0 ^ w1 of threefry(key, 0, flat_index); u = (bits>>9|1.0f)-1
//   sample : u < p
//   sigmoid: 1/(1+cephes_expf(-pre)), noFMA Horner, trailing max(res,x)
//   dot    : f32 sequential ascending-k, folded at kc=320 panel boundaries
// R12: 128x128 tile, 8m x 8n per-thread (1.0 LDS-B/FMA, at the 128 B/cyc/CU
// LDS ceiling instead of 1.5x over it).
// R13 fix: R12 regressed because __launch_bounds__(256,4) capped VGPRs at 128
// and the allocator settled at 64, spilling the 64-reg accumulator tile to
// scratch (WRITE_SIZE 186->295 MB, VALUBusy 82->57%). Live set is ~115 regs
// (64 acc + 32 B-frag + 4 A-frag + addressing). (256,3) raises the cap to
// 170 while still guaranteeing >=3 blocks/CU (LDS 32KiB/block allows 5).
// Per-output k-chain (c outer asc, cc inner asc) and fold order unchanged
// -> bit-exact.
// ============================================================================

#define TF_ROT(x, r) (((x) << (r)) | ((x) >> (32 - (r))))

__host__ __device__ __forceinline__ void threefry2x32(
    uint32_t k0, uint32_t k1, uint32_t x0, uint32_t x1,
    uint32_t &o0, uint32_t &o1) {
  const uint32_t ks2 = k0 ^ k1 ^ 0x1BD11BDAu;
  x0 += k0; x1 += k1;
#define TF_R(r) { x0 += x1; x1 = TF_ROT(x1, r); x1 ^= x0; }
  TF_R(13) TF_R(15) TF_R(26) TF_R(6)
  x0 += k1; x1 += ks2 + 1u;
  TF_R(17) TF_R(29) TF_R(16) TF_R(24)
  x0 += ks2; x1 += k0 + 2u;
  TF_R(13) TF_R(15) TF_R(26) TF_R(6)
  x0 += k0; x1 += k1 + 3u;
  TF_R(17) TF_R(29) TF_R(16) TF_R(24)
  x0 += k1; x1 += ks2 + 4u;
  TF_R(13) TF_R(15) TF_R(26) TF_R(6)
  x0 += ks2; x1 += k0 + 5u;
#undef TF_R
  o0 = x0; o1 = x1;
}

// Cephes expf, noFMA (verified in-chain).
__device__ __forceinline__ float cephes_expf(float xin) {
  float xc = fminf(xin, 88.3762626647950f);
  xc = fmaxf(xc, -88.3762626647949f);
  float fx = floorf(xc * 1.44269504088896341f + 0.5f);
  float tmp = 0.693359375f * fx;
  float z2  = -2.12194440e-4f * fx;
  float x = xc - tmp;
  x = x - z2;
  float z = x * x;
  float y = 1.9875691500E-4f * x + 1.3981999507E-3f;
  y = y * x + 8.3334519073E-3f;
  y = y * x + 4.1665795894E-2f;
  y = y * x + 1.6666665459E-1f;
  y = y * x + 5.0000001201E-1f;
  y = y * z + x;
  y = 1.0f + y;
  int n = (int)fx;
  float p2n = __uint_as_float((uint32_t)(n + 127) << 23);
  return fmaxf(y * p2n, xin);
}

__device__ __forceinline__ float sample_val(
    float tot, float bias, long b, int ng, int N_total,
    uint32_t k0, uint32_t k1) {
  float pre = tot + bias;
  float p   = 1.0f / (1.0f + cephes_expf(-pre));
  uint32_t flat = (uint32_t)(b * N_total + ng);
  uint32_t w0, w1;
  threefry2x32(k0, k1, 0u, flat, w0, w1);
  uint32_t bits = w0 ^ w1;
  float u = __uint_as_float((bits >> 9) | 0x3f800000u) - 1.0f;
  return (u < p) ? 1.0f : 0.0f;
}

// async global->LDS, 16B per lane; LDS dest = uniform base + lane*16.
__device__ __forceinline__ void gl2lds16(const float* g, float* l) {
  __builtin_amdgcn_global_load_lds(
      (const __attribute__((address_space(1))) void*)g,
      (__attribute__((address_space(3))) void*)l, 16, 0, 0);
}

// ----------------------------------------------------------------------------
// Main GEMM, 128x128 tile, BK=32, 256 threads, 8m x 8n per thread.
// A [Mtot,lda] row-major (k-contig); Bkm [K,ldb] k-major (n-contig rows).
// Thread (tx=t&15, ty=t>>4): rows m = ty+16*i (i=0..7), cols n = 4*tx+64*jq+e.
// SAMPLE=1: full K (single panel, K<=320 use only), fused sigmoid+threefry.
// SAMPLE=0: split-K partial over panel [z*320, min(K, z*320+320)) -> partials.
// Per-output chain: k = 32*tk + 4*c + cc, c outer asc, cc inner asc (exact).
// ----------------------------------------------------------------------------
template <bool SAMPLE>
__global__ __launch_bounds__(256, 3) void gemm_tile128(
    const float* __restrict__ A,     // [Mtot, lda]
    const float* __restrict__ Bkm,   // [K, ldb] k-major
    const float* __restrict__ bias,  // [N_total] (SAMPLE only)
    float* __restrict__ out,
    int lda, int ldb, int N_total, int K, int Mtot,
    uint32_t k0, uint32_t k1)
{
  __shared__ float As[128 * 32];    // [m][k] unpadded (lds-dma linear layout)
  __shared__ float Bs[32 * 128];    // [k][n] unpadded
  const int t  = threadIdx.x;
  const int tx = t & 15;
  const int ty = t >> 4;
  const int w  = t >> 6;            // wave id
  const int bm = blockIdx.x;
  const int j0 = blockIdx.y << 7;

  int kb, ke;
  float* outp = out;
  if (SAMPLE) { kb = 0; ke = K; }
  else {
    const int z = blockIdx.z;
    kb = z * 320;
    ke = min(K, kb + 320);
    outp = out + (size_t)z * Mtot * 128;
  }

  float cur[8][8];
#pragma unroll
  for (int i = 0; i < 8; ++i)
#pragma unroll
    for (int j = 0; j < 8; ++j) cur[i][j] = 0.0f;

  const long arow = (long)bm * 128 * lda;
  const int nt = (ke - kb) >> 5;    // k-tiles in this block's range

  // Per-thread staging source pointers (advance 32 cols / 32 rows per tile).
  // A tile: 1024 f4 slots, 4 rounds; slot = r*256+t; m = 32r + (t>>3), c = t&7.
  // B tile: 1024 f4 slots, 4 rounds; slot = r*256+t; kk = 8r + (t>>5), nc = t&31.
  const long aStepR = (long)32 * lda;   // A rows advance per round
  const long bStepR = (long)8  * ldb;   // B rows advance per round
  const float* aG = A + arow + (long)(t >> 3) * lda + 4 * (t & 7) + kb;
  const float* bG = Bkm + (long)(t >> 5) * ldb + j0 + 4 * (t & 31) + (long)kb * ldb;
  const long bStepT = (long)32 * ldb;   // B advance per k-tile

  const float* aP = As + ty * 32;
  const float* bP = Bs + 4 * tx;

  for (int tk = 0; tk < nt; ++tk) {
    __syncthreads();   // protect LDS reuse (prev tile's reads done)
#pragma unroll
    for (int r = 0; r < 4; ++r)
      gl2lds16(aG + r * aStepR, As + (r * 256 + w * 64) * 4);
#pragma unroll
    for (int r = 0; r < 4; ++r)
      gl2lds16(bG + r * bStepR, Bs + (r * 256 + w * 64) * 4);
    __syncthreads();   // vmcnt(0) drain: staged data visible

    // ---- compute: k ascending 4c+cc per output; B regs live across i ----
#pragma unroll
    for (int c = 0; c < 8; ++c) {
      float4 bq[4][2];
#pragma unroll
      for (int cc = 0; cc < 4; ++cc) {
        const float* brow = bP + (4 * c + cc) * 128;
        bq[cc][0] = *(const float4*)(brow);
        bq[cc][1] = *(const float4*)(brow + 64);
      }
#pragma unroll
      for (int i = 0; i < 8; ++i) {
        const float4 av = *(const float4*)(aP + i * 16 * 32 + 4 * c);
#pragma unroll
        for (int cc = 0; cc < 4; ++cc) {
          const float a = ((const float*)&av)[cc];
          cur[i][0] = __fmaf_rn(a, bq[cc][0].x, cur[i][0]);
          cur[i][1] = __fmaf_rn(a, bq[cc][0].y, cur[i][1]);
          cur[i][2] = __fmaf_rn(a, bq[cc][0].z, cur[i][2]);
          cur[i][3] = __fmaf_rn(a, bq[cc][0].w, cur[i][3]);
          cur[i][4] = __fmaf_rn(a, bq[cc][1].x, cur[i][4]);
          cur[i][5] = __fmaf_rn(a, bq[cc][1].y, cur[i][5]);
          cur[i][6] = __fmaf_rn(a, bq[cc][1].z, cur[i][6]);
          cur[i][7] = __fmaf_rn(a, bq[cc][1].w, cur[i][7]);
        }
      }
    }
    aG += 32;
    bG += bStepT;
  }

  // ---- epilogue: per (i,jq), 4 consecutive cols -> one float4 store ----
#pragma unroll
  for (int i = 0; i < 8; ++i) {
    const int m = ty + 16 * i;
    const long b = (long)bm * 128 + m;
#pragma unroll
    for (int jq = 0; jq < 2; ++jq) {
      const int n0 = 4 * tx + 64 * jq;
      float4 o;
      if (SAMPLE) {
        const int ng = j0 + n0;
        o.x = sample_val(cur[i][4 * jq + 0], bias[ng],     b, ng,     N_total, k0, k1);
        o.y = sample_val(cur[i][4 * jq + 1], bias[ng + 1], b, ng + 1, N_total, k0, k1);
        o.z = sample_val(cur[i][4 * jq + 2], bias[ng + 2], b, ng + 2, N_total, k0, k1);
        o.w = sample_val(cur[i][4 * jq + 3], bias[ng + 3], b, ng + 3, N_total, k0, k1);
        *(float4*)(outp + b * N_total + ng) = o;
      } else {
        o.x = cur[i][4 * jq + 0]; o.y = cur[i][4 * jq + 1];
        o.z = cur[i][4 * jq + 2]; o.w = cur[i][4 * jq + 3];
        *(float4*)(outp + b * 128 + n0) = o;   // j0==0, N_total==128
      }
    }
  }
}

// ----------------------------------------------------------------------------
// Fallback (no-workspace path only): previous 64x128 kernel, SAMPLE over full
// K with in-kernel panel folds (tiles_per_panel=10). Kept verbatim for the
// ws-short case; not used when split-K workspace is available.
// ----------------------------------------------------------------------------
__global__ __launch_bounds__(256, 5) void gemm_fb(
    const float* __restrict__ A,     // [Mtot, lda]
    const float* __restrict__ Bkm,   // [K, ldb] k-major
    const float* __restrict__ bias,  // [N_total]
    float* __restrict__ out,
    int lda, int ldb, int N_total, int K, int tiles_per_panel, int Mtot,
    uint32_t k0, uint32_t k1)
{
  __shared__ float As[64 * 32];
  __shared__ float Bs[32 * 128];
  const int t  = threadIdx.x;
  const int tx = t & 15;
  const int ty = t >> 4;
  const int w  = t >> 6;
  const int bm = blockIdx.x;
  const int j0 = blockIdx.y << 7;

  const int kb = 0, ke = K;

  float cur[4][8];
  float tot[4][8];
#pragma unroll
  for (int i = 0; i < 4; ++i)
#pragma unroll
    for (int j = 0; j < 8; ++j) { cur[i][j] = 0.0f; tot[i][j] = 0.0f; }

  const long arow = (long)bm * 64 * lda;
  const int t0 = kb >> 5, t1 = ke >> 5;

  const float* aP = As + ty * 32;
  const float* bP = Bs + 4 * tx;

  for (int tki = t0; tki < t1; ++tki) {
    const int kc = tki << 5;
    __syncthreads();
#pragma unroll
    for (int r = 0; r < 2; ++r) {
      int slot = r * 256 + t;
      int m = slot >> 3, c = slot & 7;
      gl2lds16(A + arow + (long)m * lda + kc + 4 * c,
               As + (r * 256 + w * 64) * 4);
    }
#pragma unroll
    for (int r = 0; r < 4; ++r) {
      int slot = r * 256 + t;
      int kk = slot >> 5, nc = slot & 31;
      gl2lds16(Bkm + (long)(kc + kk) * ldb + j0 + 4 * nc,
               Bs + (r * 256 + w * 64) * 4);
    }
    __syncthreads();

#pragma unroll
    for (int c = 0; c < 8; ++c) {
      float4 av[4];
#pragma unroll
      for (int i = 0; i < 4; ++i)
        av[i] = *(const float4*)(aP + i * 16 * 32 + 4 * c);
#pragma unroll
      for (int cc = 0; cc < 4; ++cc) {
        const float* brow = bP + (4 * c + cc) * 128;
        float4 b0 = *(const float4*)(brow);
        float4 b1 = *(const float4*)(brow + 64);
#pragma unroll
        for (int i = 0; i < 4; ++i) {
          const float a = ((const float*)&av[i])[cc];
          cur[i][0] = __fmaf_rn(a, b0.x, cur[i][0]);
          cur[i][1] = __fmaf_rn(a, b0.y, cur[i][1]);
          cur[i][2] = __fmaf_rn(a, b0.z, cur[i][2]);
          cur[i][3] = __fmaf_rn(a, b0.w, cur[i][3]);
          cur[i][4] = __fmaf_rn(a, b1.x, cur[i][4]);
          cur[i][5] = __fmaf_rn(a, b1.y, cur[i][5]);
          cur[i][6] = __fmaf_rn(a, b1.z, cur[i][6]);
          cur[i][7] = __fmaf_rn(a, b1.w, cur[i][7]);
        }
      }
    }

    if (((tki - t0 + 1) % tiles_per_panel == 0) || (tki == t1 - 1)) {
#pragma unroll
      for (int i = 0; i < 4; ++i)
#pragma unroll
        for (int j = 0; j < 8; ++j) { tot[i][j] += cur[i][j]; cur[i][j] = 0.0f; }
    }
  }

#pragma unroll
  for (int i = 0; i < 4; ++i) {
    const int m = ty + 16 * i;
    const long b = (long)bm * 64 + m;
#pragma unroll
    for (int jq = 0; jq < 2; ++jq) {
      const int n0 = 4 * tx + 64 * jq;
      const int ng = j0 + n0;
      float4 o;
      o.x = sample_val(tot[i][4 * jq + 0], bias[ng],     b, ng,     N_total, k0, k1);
      o.y = sample_val(tot[i][4 * jq + 1], bias[ng + 1], b, ng + 1, N_total, k0, k1);
      o.z = sample_val(tot[i][4 * jq + 2], bias[ng + 2], b, ng + 2, N_total, k0, k1);
      o.w = sample_val(tot[i][4 * jq + 3], bias[ng + 3], b, ng + 3, N_total, k0, k1);
      *(float4*)(out + b * N_total + ng) = o;
    }
  }
}

// Fold 4 panel partials in exact order, then bias+sigmoid+sample.
__global__ __launch_bounds__(256) void combine_sample(
    const float* __restrict__ partials,  // [4][Mtot*128]
    const float* __restrict__ bias,      // [128]
    float* __restrict__ out,             // [Mtot*128] binary f32
    int Mtot, uint32_t k0, uint32_t k1)
{
  const long idx = (long)blockIdx.x * 256 + threadIdx.x;
  const long S = (long)Mtot * 128;
  float p0 = partials[idx];
  float p1 = partials[S + idx];
  float p2 = partials[2 * S + idx];
  float p3 = partials[3 * S + idx];
  float tot = ((p0 + p1) + p2) + p3;          // Eigen fold order, exact
  float pre = tot + bias[(int)(idx & 127)];
  float p   = 1.0f / (1.0f + cephes_expf(-pre));
  uint32_t w0, w1;
  threefry2x32(k0, k1, 0u, (uint32_t)idx, w0, w1);
  uint32_t bits = w0 ^ w1;
  float u = __uint_as_float((bits >> 9) | 0x3f800000u) - 1.0f;
  out[idx] = (u < p) ? 1.0f : 0.0f;
}

__global__ void transpose_W(const float* __restrict__ W, float* __restrict__ Wt) {
  __shared__ float tile[32][33];
  int bx = blockIdx.x, by = blockIdx.y;
  int x = threadIdx.x, y = threadIdx.y;
  tile[y][x] = W[(by * 32 + y) * 1024 + bx * 32 + x];
  __syncthreads();
  Wt[(bx * 32 + y) * 128 + by * 32 + x] = tile[x][y];
}

extern "C" void kernel_launch(void* const* d_in, const int* in_sizes, int n_in,
                              void* d_out, int out_size, void* d_ws, size_t ws_size,
                              hipStream_t stream) {
  const float* v0 = (const float*)d_in[0];   // [B,1024]
  const float* W  = (const float*)d_in[1];   // [128,1024]
  const float* bb = (const float*)d_in[2];   // [1024]
  const float* cb = (const float*)d_in[3];   // [128]
  const int B = in_sizes[0] / 1024;          // 32768

  float* out    = (float*)d_out;
  float* out_v  = out;                        // v_given_h   [B,1024]
  float* out_h1 = out + (size_t)B * 1024;     // h_given_v   [B,128]
  float* out_h2 = out_h1 + (size_t)B * 128;   // h_given_v_0 [B,128]

  float* Wt       = (float*)d_ws;                       // [1024,128] k-major for h-GEMM
  float* h_ws     = Wt + 1024 * 128;                    // [B,128]
  float* partials = h_ws + (size_t)B * 128;             // [4][B,128]
  const size_t need = (size_t)(1024 * 128 + (size_t)B * 128 * 5) * 4;
  const bool use_split = ws_size >= need;

  // partitionable keys: seed 42, fold-like split
  uint32_t kt[5][2], kv[5][2], kh[5][2];
  for (uint32_t i = 0; i < 5; ++i) threefry2x32(0u, 42u, 0u, i, kt[i][0], kt[i][1]);
  for (int t = 1; t <= 4; ++t) {
    threefry2x32(kt[t][0], kt[t][1], 0u, 0u, kv[t][0], kv[t][1]);
    threefry2x32(kt[t][0], kt[t][1], 0u, 1u, kh[t][0], kh[t][1]);
  }

  transpose_W<<<dim3(32, 4), dim3(32, 32), 0, stream>>>(W, Wt);

  const int MB = B / 128;    // 256 row-blocks (128-row tiles)

  // h-step: hdst = bernoulli(key, sigmoid(W vin + c)); Bkm = Wt (ldb=128)
  auto h_step = [&](const float* vin, float* hdst, uint32_t hk0, uint32_t hk1) {
    if (use_split) {
      gemm_tile128<false><<<dim3(MB, 1, 4), 256, 0, stream>>>(
          vin, Wt, nullptr, partials, 1024, 128, 128, 1024, B, 0u, 0u);
      combine_sample<<<dim3(B * 128 / 256), 256, 0, stream>>>(
          partials, cb, hdst, B, hk0, hk1);
    } else {
      gemm_fb<<<dim3(B / 64, 1, 1), 256, 0, stream>>>(
          vin, Wt, cb, hdst, 1024, 128, 128, 1024, 10, B, hk0, hk1);
    }
  };

  // h0 = bernoulli(kt[0], sigmoid(W v0 + c))
  h_step(v0, out_h2, kt[0][0], kt[0][1]);

  const float* h = out_h2;
  for (int t = 1; t <= 4; ++t) {
    // v_t = bernoulli(kv[t], sigmoid(W^T h + b)) — K=128 (<320, single panel)
    gemm_tile128<true><<<dim3(MB, 8, 1), 256, 0, stream>>>(
        h, W, bb, out_v, 128, 1024, 1024, 128, B, kv[t][0], kv[t][1]);
    // h_t = bernoulli(kh[t], sigmoid(W v_t + c))
    float* hdst = (t == 4) ? out_h1 : h_ws;
    h_step(out_v, hdst, kh[t][0], kh[t][1]);
    h = hdst;
  }
}

// Round 3
// 1388.380 us; speedup vs baseline: 1.2055x; 1.0115x over previous
//
#include <hip/hip_runtime.h>
#include <cstdint>

// ============================================================================
// RBM_BB block Gibbs, bit-exact (recipe frozen, R3/R5/R6/R7-verified):
//   keys   : partitionable threefry; fold-like split key_i = threefry(parent,0,i)
//   bits   : w0 ^ w1 of threefry(key, 0, flat_index); u = (bits>>9|1.0f)-1
//   sample : u < p
//   sigmoid: 1/(1+cephes_expf(-pre)), noFMA Horner, trailing max(res,x)
//   dot    : f32 sequential ascending-k, folded at kc=320 panel boundaries
// R12: 128x128 tile, 8m x 8n per-thread (1.0 LDS-B/FMA).
// R13: __launch_bounds__(256,3) — (256,4) capped VGPR at 128, allocator chose
//      64 and spilled the acc tile (WRITE 295 MB). At (256,3): VGPR 80, no
//      spill, h-GEMM 272->~110 us.
// R14: VALU-issue reduction. v-GEMM (SAMPLE, K=128) measured 195 us at
// VALUBusy 83% = instruction-bound: 55 us FMA floor + ~45 us frozen-recipe
// epilogue. (a) v_pk_fma_f32 via float2 __builtin_elementwise_fma — halves
// FMA issue; each output keeps its own IEEE-fma chain (pairs are adjacent
// output columns) -> bit-exact. (b) threefry rotates forced to
// v_alignbit_b32. Per-output k-chain (c outer asc, cc inner asc) and fold
// order unchanged -> bit-exact.
// ============================================================================

typedef float f32x2 __attribute__((ext_vector_type(2)));

__host__ __device__ __forceinline__ uint32_t tf_rot(uint32_t x, int r) {
#ifdef __HIP_DEVICE_COMPILE__
  return __builtin_amdgcn_alignbit(x, x, (uint32_t)(32 - r));  // rotl(x,r)
#else
  return (x << r) | (x >> (32 - r));
#endif
}

__host__ __device__ __forceinline__ void threefry2x32(
    uint32_t k0, uint32_t k1, uint32_t x0, uint32_t x1,
    uint32_t &o0, uint32_t &o1) {
  const uint32_t ks2 = k0 ^ k1 ^ 0x1BD11BDAu;
  x0 += k0; x1 += k1;
#define TF_R(r) { x0 += x1; x1 = tf_rot(x1, r); x1 ^= x0; }
  TF_R(13) TF_R(15) TF_R(26) TF_R(6)
  x0 += k1; x1 += ks2 + 1u;
  TF_R(17) TF_R(29) TF_R(16) TF_R(24)
  x0 += ks2; x1 += k0 + 2u;
  TF_R(13) TF_R(15) TF_R(26) TF_R(6)
  x0 += k0; x1 += k1 + 3u;
  TF_R(17) TF_R(29) TF_R(16) TF_R(24)
  x0 += k1; x1 += ks2 + 4u;
  TF_R(13) TF_R(15) TF_R(26) TF_R(6)
  x0 += ks2; x1 += k0 + 5u;
#undef TF_R
  o0 = x0; o1 = x1;
}

// Cephes expf, noFMA (verified in-chain).
__device__ __forceinline__ float cephes_expf(float xin) {
  float xc = fminf(xin, 88.3762626647950f);
  xc = fmaxf(xc, -88.3762626647949f);
  float fx = floorf(xc * 1.44269504088896341f + 0.5f);
  float tmp = 0.693359375f * fx;
  float z2  = -2.12194440e-4f * fx;
  float x = xc - tmp;
  x = x - z2;
  float z = x * x;
  float y = 1.9875691500E-4f * x + 1.3981999507E-3f;
  y = y * x + 8.3334519073E-3f;
  y = y * x + 4.1665795894E-2f;
  y = y * x + 1.6666665459E-1f;
  y = y * x + 5.0000001201E-1f;
  y = y * z + x;
  y = 1.0f + y;
  int n = (int)fx;
  float p2n = __uint_as_float((uint32_t)(n + 127) << 23);
  return fmaxf(y * p2n, xin);
}

__device__ __forceinline__ float sample_val(
    float tot, float bias, long b, int ng, int N_total,
    uint32_t k0, uint32_t k1) {
  float pre = tot + bias;
  float p   = 1.0f / (1.0f + cephes_expf(-pre));
  uint32_t flat = (uint32_t)(b * N_total + ng);
  uint32_t w0, w1;
  threefry2x32(k0, k1, 0u, flat, w0, w1);
  uint32_t bits = w0 ^ w1;
  float u = __uint_as_float((bits >> 9) | 0x3f800000u) - 1.0f;
  return (u < p) ? 1.0f : 0.0f;
}

// async global->LDS, 16B per lane; LDS dest = uniform base + lane*16.
__device__ __forceinline__ void gl2lds16(const float* g, float* l) {
  __builtin_amdgcn_global_load_lds(
      (const __attribute__((address_space(1))) void*)g,
      (__attribute__((address_space(3))) void*)l, 16, 0, 0);
}

// ----------------------------------------------------------------------------
// Main GEMM, 128x128 tile, BK=32, 256 threads, 8m x 8n per thread.
// A [Mtot,lda] row-major (k-contig); Bkm [K, ldb] k-major (n-contig rows).
// Thread (tx=t&15, ty=t>>4): rows m = ty+16*i (i=0..7), cols n = 4*tx+64*jq+e.
// Accumulators as f32x2 pairs of ADJACENT columns -> v_pk_fma_f32; each
// column keeps an independent IEEE-fma chain (bit-exact vs scalar).
// SAMPLE=1: full K (single panel, K<=320 use only), fused sigmoid+threefry.
// SAMPLE=0: split-K partial over panel [z*320, min(K, z*320+320)) -> partials.
// Per-output chain: k = 32*tk + 4*c + cc, c outer asc, cc inner asc (exact).
// ----------------------------------------------------------------------------
template <bool SAMPLE>
__global__ __launch_bounds__(256, 3) void gemm_tile128(
    const float* __restrict__ A,     // [Mtot, lda]
    const float* __restrict__ Bkm,   // [K, ldb] k-major
    const float* __restrict__ bias,  // [N_total] (SAMPLE only)
    float* __restrict__ out,
    int lda, int ldb, int N_total, int K, int Mtot,
    uint32_t k0, uint32_t k1)
{
  __shared__ float As[128 * 32];    // [m][k] unpadded (lds-dma linear layout)
  __shared__ float Bs[32 * 128];    // [k][n] unpadded
  const int t  = threadIdx.x;
  const int tx = t & 15;
  const int ty = t >> 4;
  const int w  = t >> 6;            // wave id
  const int bm = blockIdx.x;
  const int j0 = blockIdx.y << 7;

  int kb, ke;
  float* outp = out;
  if (SAMPLE) { kb = 0; ke = K; }
  else {
    const int z = blockIdx.z;
    kb = z * 320;
    ke = min(K, kb + 320);
    outp = out + (size_t)z * Mtot * 128;
  }

  // cur[i][q]: q=0,1 -> cols 4tx+{0,1},{2,3}; q=2,3 -> cols 4tx+64+{0,1},{2,3}
  f32x2 cur[8][4];
#pragma unroll
  for (int i = 0; i < 8; ++i)
#pragma unroll
    for (int q = 0; q < 4; ++q) cur[i][q] = f32x2{0.0f, 0.0f};

  const long arow = (long)bm * 128 * lda;
  const int nt = (ke - kb) >> 5;    // k-tiles in this block's range

  // A tile: 1024 f4 slots, 4 rounds; slot = r*256+t; m = 32r + (t>>3), c = t&7.
  // B tile: 1024 f4 slots, 4 rounds; slot = r*256+t; kk = 8r + (t>>5), nc = t&31.
  const long aStepR = (long)32 * lda;   // A rows advance per round
  const long bStepR = (long)8  * ldb;   // B rows advance per round
  const float* aG = A + arow + (long)(t >> 3) * lda + 4 * (t & 7) + kb;
  const float* bG = Bkm + (long)(t >> 5) * ldb + j0 + 4 * (t & 31) + (long)kb * ldb;
  const long bStepT = (long)32 * ldb;   // B advance per k-tile

  const float* aP = As + ty * 32;
  const float* bP = Bs + 4 * tx;

  for (int tk = 0; tk < nt; ++tk) {
    __syncthreads();   // protect LDS reuse (prev tile's reads done)
#pragma unroll
    for (int r = 0; r < 4; ++r)
      gl2lds16(aG + r * aStepR, As + (r * 256 + w * 64) * 4);
#pragma unroll
    for (int r = 0; r < 4; ++r)
      gl2lds16(bG + r * bStepR, Bs + (r * 256 + w * 64) * 4);
    __syncthreads();   // vmcnt(0) drain: staged data visible

    // ---- compute: k ascending 4c+cc per output; B regs live across i ----
#pragma unroll
    for (int c = 0; c < 8; ++c) {
      float4 b0[4], b1[4];
#pragma unroll
      for (int cc = 0; cc < 4; ++cc) {
        const float* brow = bP + (4 * c + cc) * 128;
        b0[cc] = *(const float4*)(brow);
        b1[cc] = *(const float4*)(brow + 64);
      }
#pragma unroll
      for (int i = 0; i < 8; ++i) {
        const float4 av = *(const float4*)(aP + i * 16 * 32 + 4 * c);
#pragma unroll
        for (int cc = 0; cc < 4; ++cc) {
          const float a = ((const float*)&av)[cc];
          const f32x2 aa = {a, a};
          const f32x2* p0 = (const f32x2*)&b0[cc];   // regs of b128 load
          const f32x2* p1 = (const f32x2*)&b1[cc];
          cur[i][0] = __builtin_elementwise_fma(aa, p0[0], cur[i][0]);
          cur[i][1] = __builtin_elementwise_fma(aa, p0[1], cur[i][1]);
          cur[i][2] = __builtin_elementwise_fma(aa, p1[0], cur[i][2]);
          cur[i][3] = __builtin_elementwise_fma(aa, p1[1], cur[i][3]);
        }
      }
    }
    aG += 32;
    bG += bStepT;
  }

  // ---- epilogue: per (i,jq), 4 consecutive cols -> one float4 store ----
#pragma unroll
  for (int i = 0; i < 8; ++i) {
    const int m = ty + 16 * i;
    const long b = (long)bm * 128 + m;
#pragma unroll
    for (int jq = 0; jq < 2; ++jq) {
      const int n0 = 4 * tx + 64 * jq;
      const f32x2 e01 = cur[i][2 * jq + 0];
      const f32x2 e23 = cur[i][2 * jq + 1];
      float4 o;
      if (SAMPLE) {
        const int ng = j0 + n0;
        o.x = sample_val(e01.x, bias[ng],     b, ng,     N_total, k0, k1);
        o.y = sample_val(e01.y, bias[ng + 1], b, ng + 1, N_total, k0, k1);
        o.z = sample_val(e23.x, bias[ng + 2], b, ng + 2, N_total, k0, k1);
        o.w = sample_val(e23.y, bias[ng + 3], b, ng + 3, N_total, k0, k1);
        *(float4*)(outp + b * N_total + ng) = o;
      } else {
        o.x = e01.x; o.y = e01.y; o.z = e23.x; o.w = e23.y;
        *(float4*)(outp + b * 128 + n0) = o;   // j0==0, N_total==128
      }
    }
  }
}

// ----------------------------------------------------------------------------
// Fallback (no-workspace path only): 64x128 kernel, SAMPLE over full K with
// in-kernel panel folds (tiles_per_panel=10). Not used when split-K workspace
// is available.
// ----------------------------------------------------------------------------
__global__ __launch_bounds__(256, 5) void gemm_fb(
    const float* __restrict__ A,     // [Mtot, lda]
    const float* __restrict__ Bkm,   // [K, ldb] k-major
    const float* __restrict__ bias,  // [N_total]
    float* __restrict__ out,
    int lda, int ldb, int N_total, int K, int tiles_per_panel, int Mtot,
    uint32_t k0, uint32_t k1)
{
  __shared__ float As[64 * 32];
  __shared__ float Bs[32 * 128];
  const int t  = threadIdx.x;
  const int tx = t & 15;
  const int ty = t >> 4;
  const int w  = t >> 6;
  const int bm = blockIdx.x;
  const int j0 = blockIdx.y << 7;

  const int kb = 0, ke = K;

  float cur[4][8];
  float tot[4][8];
#pragma unroll
  for (int i = 0; i < 4; ++i)
#pragma unroll
    for (int j = 0; j < 8; ++j) { cur[i][j] = 0.0f; tot[i][j] = 0.0f; }

  const long arow = (long)bm * 64 * lda;
  const int t0 = kb >> 5, t1 = ke >> 5;

  const float* aP = As + ty * 32;
  const float* bP = Bs + 4 * tx;

  for (int tki = t0; tki < t1; ++tki) {
    const int kc = tki << 5;
    __syncthreads();
#pragma unroll
    for (int r = 0; r < 2; ++r) {
      int slot = r * 256 + t;
      int m = slot >> 3, c = slot & 7;
      gl2lds16(A + arow + (long)m * lda + kc + 4 * c,
               As + (r * 256 + w * 64) * 4);
    }
#pragma unroll
    for (int r = 0; r < 4; ++r) {
      int slot = r * 256 + t;
      int kk = slot >> 5, nc = slot & 31;
      gl2lds16(Bkm + (long)(kc + kk) * ldb + j0 + 4 * nc,
               Bs + (r * 256 + w * 64) * 4);
    }
    __syncthreads();

#pragma unroll
    for (int c = 0; c < 8; ++c) {
      float4 av[4];
#pragma unroll
      for (int i = 0; i < 4; ++i)
        av[i] = *(const float4*)(aP + i * 16 * 32 + 4 * c);
#pragma unroll
      for (int cc = 0; cc < 4; ++cc) {
        const float* brow = bP + (4 * c + cc) * 128;
        float4 b0 = *(const float4*)(brow);
        float4 b1 = *(const float4*)(brow + 64);
#pragma unroll
        for (int i = 0; i < 4; ++i) {
          const float a = ((const float*)&av[i])[cc];
          cur[i][0] = __fmaf_rn(a, b0.x, cur[i][0]);
          cur[i][1] = __fmaf_rn(a, b0.y, cur[i][1]);
          cur[i][2] = __fmaf_rn(a, b0.z, cur[i][2]);
          cur[i][3] = __fmaf_rn(a, b0.w, cur[i][3]);
          cur[i][4] = __fmaf_rn(a, b1.x, cur[i][4]);
          cur[i][5] = __fmaf_rn(a, b1.y, cur[i][5]);
          cur[i][6] = __fmaf_rn(a, b1.z, cur[i][6]);
          cur[i][7] = __fmaf_rn(a, b1.w, cur[i][7]);
        }
      }
    }

    if (((tki - t0 + 1) % tiles_per_panel == 0) || (tki == t1 - 1)) {
#pragma unroll
      for (int i = 0; i < 4; ++i)
#pragma unroll
        for (int j = 0; j < 8; ++j) { tot[i][j] += cur[i][j]; cur[i][j] = 0.0f; }
    }
  }

#pragma unroll
  for (int i = 0; i < 4; ++i) {
    const int m = ty + 16 * i;
    const long b = (long)bm * 64 + m;
#pragma unroll
    for (int jq = 0; jq < 2; ++jq) {
      const int n0 = 4 * tx + 64 * jq;
      const int ng = j0 + n0;
      float4 o;
      o.x = sample_val(tot[i][4 * jq + 0], bias[ng],     b, ng,     N_total, k0, k1);
      o.y = sample_val(tot[i][4 * jq + 1], bias[ng + 1], b, ng + 1, N_total, k0, k1);
      o.z = sample_val(tot[i][4 * jq + 2], bias[ng + 2], b, ng + 2, N_total, k0, k1);
      o.w = sample_val(tot[i][4 * jq + 3], bias[ng + 3], b, ng + 3, N_total, k0, k1);
      *(float4*)(out + b * N_total + ng) = o;
    }
  }
}

// Fold 4 panel partials in exact order, then bias+sigmoid+sample.
__global__ __launch_bounds__(256) void combine_sample(
    const float* __restrict__ partials,  // [4][Mtot*128]
    const float* __restrict__ bias,      // [128]
    float* __restrict__ out,             // [Mtot*128] binary f32
    int Mtot, uint32_t k0, uint32_t k1)
{
  const long idx = (long)blockIdx.x * 256 + threadIdx.x;
  const long S = (long)Mtot * 128;
  float p0 = partials[idx];
  float p1 = partials[S + idx];
  float p2 = partials[2 * S + idx];
  float p3 = partials[3 * S + idx];
  float tot = ((p0 + p1) + p2) + p3;          // Eigen fold order, exact
  float pre = tot + bias[(int)(idx & 127)];
  float p   = 1.0f / (1.0f + cephes_expf(-pre));
  uint32_t w0, w1;
  threefry2x32(k0, k1, 0u, (uint32_t)idx, w0, w1);
  uint32_t bits = w0 ^ w1;
  float u = __uint_as_float((bits >> 9) | 0x3f800000u) - 1.0f;
  out[idx] = (u < p) ? 1.0f : 0.0f;
}

__global__ void transpose_W(const float* __restrict__ W, float* __restrict__ Wt) {
  __shared__ float tile[32][33];
  int bx = blockIdx.x, by = blockIdx.y;
  int x = threadIdx.x, y = threadIdx.y;
  tile[y][x] = W[(by * 32 + y) * 1024 + bx * 32 + x];
  __syncthreads();
  Wt[(bx * 32 + y) * 128 + by * 32 + x] = tile[x][y];
}

extern "C" void kernel_launch(void* const* d_in, const int* in_sizes, int n_in,
                              void* d_out, int out_size, void* d_ws, size_t ws_size,
                              hipStream_t stream) {
  const float* v0 = (const float*)d_in[0];   // [B,1024]
  const float* W  = (const float*)d_in[1];   // [128,1024]
  const float* bb = (const float*)d_in[2];   // [1024]
  const float* cb = (const float*)d_in[3];   // [128]
  const int B = in_sizes[0] / 1024;          // 32768

  float* out    = (float*)d_out;
  float* out_v  = out;                        // v_given_h   [B,1024]
  float* out_h1 = out + (size_t)B * 1024;     // h_given_v   [B,128]
  float* out_h2 = out_h1 + (size_t)B * 128;   // h_given_v_0 [B,128]

  float* Wt       = (float*)d_ws;                       // [1024,128] k-major for h-GEMM
  float* h_ws     = Wt + 1024 * 128;                    // [B,128]
  float* partials = h_ws + (size_t)B * 128;             // [4][B,128]
  const size_t need = (size_t)(1024 * 128 + (size_t)B * 128 * 5) * 4;
  const bool use_split = ws_size >= need;

  // partitionable keys: seed 42, fold-like split
  uint32_t kt[5][2], kv[5][2], kh[5][2];
  for (uint32_t i = 0; i < 5; ++i) threefry2x32(0u, 42u, 0u, i, kt[i][0], kt[i][1]);
  for (int t = 1; t <= 4; ++t) {
    threefry2x32(kt[t][0], kt[t][1], 0u, 0u, kv[t][0], kv[t][1]);
    threefry2x32(kt[t][0], kt[t][1], 0u, 1u, kh[t][0], kh[t][1]);
  }

  transpose_W<<<dim3(32, 4), dim3(32, 32), 0, stream>>>(W, Wt);

  const int MB = B / 128;    // 256 row-blocks (128-row tiles)

  // h-step: hdst = bernoulli(key, sigmoid(W vin + c)); Bkm = Wt (ldb=128)
  auto h_step = [&](const float* vin, float* hdst, uint32_t hk0, uint32_t hk1) {
    if (use_split) {
      gemm_tile128<false><<<dim3(MB, 1, 4), 256, 0, stream>>>(
          vin, Wt, nullptr, partials, 1024, 128, 128, 1024, B, 0u, 0u);
      combine_sample<<<dim3(B * 128 / 256), 256, 0, stream>>>(
          partials, cb, hdst, B, hk0, hk1);
    } else {
      gemm_fb<<<dim3(B / 64, 1, 1), 256, 0, stream>>>(
          vin, Wt, cb, hdst, 1024, 128, 128, 1024, 10, B, hk0, hk1);
    }
  };

  // h0 = bernoulli(kt[0], sigmoid(W v0 + c))
  h_step(v0, out_h2, kt[0][0], kt[0][1]);

  const float* h = out_h2;
  for (int t = 1; t <= 4; ++t) {
    // v_t = bernoulli(kv[t], sigmoid(W^T h + b)) — K=128 (<320, single panel)
    gemm_tile128<true><<<dim3(MB, 8, 1), 256, 0, stream>>>(
        h, W, bb, out_v, 128, 1024, 1024, 128, B, kv[t][0], kv[t][1]);
    // h_t = bernoulli(kh[t], sigmoid(W v_t + c))
    float* hdst = (t == 4) ? out_h1 : h_ws;
    h_step(out_v, hdst, kh[t][0], kh[t][1]);
    h = hdst;
  }
}

// Round 4
// 1369.706 us; speedup vs baseline: 1.2219x; 1.0136x over previous
//
#include <hip/hip_runtime.h>
#include <cstdint>

// ============================================================================
// RBM_BB block Gibbs, bit-exact (recipe frozen, R3/R5/R6/R7-verified):
//   keys   : partitionable threefry; fold-like split key_i = threefry(parent,0,i)
//   bits   : w0 ^ w1 of threefry(key, 0, flat_index); u = (bits>>9|1.0f)-1
//   sample : u < p
//   sigmoid: 1/(1+cephes_expf(-pre)), noFMA Horner, trailing max(res,x)
//   dot    : f32 sequential ascending-k, folded at kc=320 panel boundaries
// R12: 128x128 tile, 8m x 8n per-thread (1.0 LDS-B/FMA).
// R13: __launch_bounds__(256,3) — avoids allocator spill (VGPR 80, no scratch).
// R14: __builtin_elementwise_fma(f32x2) was SCALARIZED (identical dur/VGPR/
//      VALUBusy vs R13) — packed fma never reached HW.
// R15: force v_pk_fma_f32 via inline asm (VOP3P). op_sel broadcasts src0
// lo/hi so the A float4 feeds 4 k-steps with zero v_movs; B pairs are
// subregisters of the ds_read_b128 quads. Each packed lane is an independent
// IEEE fma; per-output k-chain (c outer asc, cc 0,1,2,3 inner asc) and fold
// order unchanged -> bit-exact.
// ============================================================================

typedef float f32x2 __attribute__((ext_vector_type(2)));

// acc.{lo,hi} += a2.lo * b2.{lo,hi}  (src0 lo broadcast)
#define PK_FMA_LO(acc, a2, b2) \
  asm("v_pk_fma_f32 %0, %1, %2, %0 op_sel:[0,0,0] op_sel_hi:[0,1,1]" \
      : "+v"(acc) : "v"(a2), "v"(b2))
// acc.{lo,hi} += a2.hi * b2.{lo,hi}  (src0 hi broadcast)
#define PK_FMA_HI(acc, a2, b2) \
  asm("v_pk_fma_f32 %0, %1, %2, %0 op_sel:[1,0,0] op_sel_hi:[1,1,1]" \
      : "+v"(acc) : "v"(a2), "v"(b2))

__host__ __device__ __forceinline__ uint32_t tf_rot(uint32_t x, int r) {
#ifdef __HIP_DEVICE_COMPILE__
  return __builtin_amdgcn_alignbit(x, x, (uint32_t)(32 - r));  // rotl(x,r)
#else
  return (x << r) | (x >> (32 - r));
#endif
}

__host__ __device__ __forceinline__ void threefry2x32(
    uint32_t k0, uint32_t k1, uint32_t x0, uint32_t x1,
    uint32_t &o0, uint32_t &o1) {
  const uint32_t ks2 = k0 ^ k1 ^ 0x1BD11BDAu;
  x0 += k0; x1 += k1;
#define TF_R(r) { x0 += x1; x1 = tf_rot(x1, r); x1 ^= x0; }
  TF_R(13) TF_R(15) TF_R(26) TF_R(6)
  x0 += k1; x1 += ks2 + 1u;
  TF_R(17) TF_R(29) TF_R(16) TF_R(24)
  x0 += ks2; x1 += k0 + 2u;
  TF_R(13) TF_R(15) TF_R(26) TF_R(6)
  x0 += k0; x1 += k1 + 3u;
  TF_R(17) TF_R(29) TF_R(16) TF_R(24)
  x0 += k1; x1 += ks2 + 4u;
  TF_R(13) TF_R(15) TF_R(26) TF_R(6)
  x0 += ks2; x1 += k0 + 5u;
#undef TF_R
  o0 = x0; o1 = x1;
}

// Cephes expf, noFMA (verified in-chain).
__device__ __forceinline__ float cephes_expf(float xin) {
  float xc = fminf(xin, 88.3762626647950f);
  xc = fmaxf(xc, -88.3762626647949f);
  float fx = floorf(xc * 1.44269504088896341f + 0.5f);
  float tmp = 0.693359375f * fx;
  float z2  = -2.12194440e-4f * fx;
  float x = xc - tmp;
  x = x - z2;
  float z = x * x;
  float y = 1.9875691500E-4f * x + 1.3981999507E-3f;
  y = y * x + 8.3334519073E-3f;
  y = y * x + 4.1665795894E-2f;
  y = y * x + 1.6666665459E-1f;
  y = y * x + 5.0000001201E-1f;
  y = y * z + x;
  y = 1.0f + y;
  int n = (int)fx;
  float p2n = __uint_as_float((uint32_t)(n + 127) << 23);
  return fmaxf(y * p2n, xin);
}

__device__ __forceinline__ float sample_val(
    float tot, float bias, long b, int ng, int N_total,
    uint32_t k0, uint32_t k1) {
  float pre = tot + bias;
  float p   = 1.0f / (1.0f + cephes_expf(-pre));
  uint32_t flat = (uint32_t)(b * N_total + ng);
  uint32_t w0, w1;
  threefry2x32(k0, k1, 0u, flat, w0, w1);
  uint32_t bits = w0 ^ w1;
  float u = __uint_as_float((bits >> 9) | 0x3f800000u) - 1.0f;
  return (u < p) ? 1.0f : 0.0f;
}

// async global->LDS, 16B per lane; LDS dest = uniform base + lane*16.
__device__ __forceinline__ void gl2lds16(const float* g, float* l) {
  __builtin_amdgcn_global_load_lds(
      (const __attribute__((address_space(1))) void*)g,
      (__attribute__((address_space(3))) void*)l, 16, 0, 0);
}

// ----------------------------------------------------------------------------
// Main GEMM, 128x128 tile, BK=32, 256 threads, 8m x 8n per thread.
// A [Mtot,lda] row-major (k-contig); Bkm [K, ldb] k-major (n-contig rows).
// Thread (tx=t&15, ty=t>>4): rows m = ty+16*i (i=0..7), cols n = 4*tx+64*jq+e.
// Accumulators: f32x2 pairs of ADJACENT columns, fed by v_pk_fma_f32 with
// op_sel src0 broadcast; each column keeps an independent IEEE-fma chain.
// SAMPLE=1: full K (single panel, K<=320 use only), fused sigmoid+threefry.
// SAMPLE=0: split-K partial over panel [z*320, min(K, z*320+320)) -> partials.
// Per-output chain: k = 32*tk + 4*c + cc, c outer asc, cc inner asc (exact).
// ----------------------------------------------------------------------------
template <bool SAMPLE>
__global__ __launch_bounds__(256, 3) void gemm_tile128(
    const float* __restrict__ A,     // [Mtot, lda]
    const float* __restrict__ Bkm,   // [K, ldb] k-major
    const float* __restrict__ bias,  // [N_total] (SAMPLE only)
    float* __restrict__ out,
    int lda, int ldb, int N_total, int K, int Mtot,
    uint32_t k0, uint32_t k1)
{
  __shared__ float As[128 * 32];    // [m][k] unpadded (lds-dma linear layout)
  __shared__ float Bs[32 * 128];    // [k][n] unpadded
  const int t  = threadIdx.x;
  const int tx = t & 15;
  const int ty = t >> 4;
  const int w  = t >> 6;            // wave id
  const int bm = blockIdx.x;
  const int j0 = blockIdx.y << 7;

  int kb, ke;
  float* outp = out;
  if (SAMPLE) { kb = 0; ke = K; }
  else {
    const int z = blockIdx.z;
    kb = z * 320;
    ke = min(K, kb + 320);
    outp = out + (size_t)z * Mtot * 128;
  }

  // cur[i][q]: q=0,1 -> cols 4tx+{0,1},{2,3}; q=2,3 -> cols 4tx+64+{0,1},{2,3}
  f32x2 cur[8][4];
#pragma unroll
  for (int i = 0; i < 8; ++i)
#pragma unroll
    for (int q = 0; q < 4; ++q) cur[i][q] = f32x2{0.0f, 0.0f};

  const long arow = (long)bm * 128 * lda;
  const int nt = (ke - kb) >> 5;    // k-tiles in this block's range

  // A tile: 1024 f4 slots, 4 rounds; slot = r*256+t; m = 32r + (t>>3), c = t&7.
  // B tile: 1024 f4 slots, 4 rounds; slot = r*256+t; kk = 8r + (t>>5), nc = t&31.
  const long aStepR = (long)32 * lda;   // A rows advance per round
  const long bStepR = (long)8  * ldb;   // B rows advance per round
  const float* aG = A + arow + (long)(t >> 3) * lda + 4 * (t & 7) + kb;
  const float* bG = Bkm + (long)(t >> 5) * ldb + j0 + 4 * (t & 31) + (long)kb * ldb;
  const long bStepT = (long)32 * ldb;   // B advance per k-tile

  const float* aP = As + ty * 32;
  const float* bP = Bs + 4 * tx;

  for (int tk = 0; tk < nt; ++tk) {
    __syncthreads();   // protect LDS reuse (prev tile's reads done)
#pragma unroll
    for (int r = 0; r < 4; ++r)
      gl2lds16(aG + r * aStepR, As + (r * 256 + w * 64) * 4);
#pragma unroll
    for (int r = 0; r < 4; ++r)
      gl2lds16(bG + r * bStepR, Bs + (r * 256 + w * 64) * 4);
    __syncthreads();   // vmcnt(0) drain: staged data visible

    // ---- compute: k ascending 4c+cc per output; B regs live across i ----
#pragma unroll
    for (int c = 0; c < 8; ++c) {
      float4 b0[4], b1[4];
#pragma unroll
      for (int cc = 0; cc < 4; ++cc) {
        const float* brow = bP + (4 * c + cc) * 128;
        b0[cc] = *(const float4*)(brow);
        b1[cc] = *(const float4*)(brow + 64);
      }
#pragma unroll
      for (int i = 0; i < 8; ++i) {
        const float4 av = *(const float4*)(aP + i * 16 * 32 + 4 * c);
        const f32x2* ap = (const f32x2*)&av;      // ap[0]={k0,k1}, ap[1]={k2,k3}
        // cc = 0: a = av.x (ap[0].lo)
        { const f32x2* q0 = (const f32x2*)&b0[0];
          const f32x2* q1 = (const f32x2*)&b1[0];
          PK_FMA_LO(cur[i][0], ap[0], q0[0]);
          PK_FMA_LO(cur[i][1], ap[0], q0[1]);
          PK_FMA_LO(cur[i][2], ap[0], q1[0]);
          PK_FMA_LO(cur[i][3], ap[0], q1[1]); }
        // cc = 1: a = av.y (ap[0].hi)
        { const f32x2* q0 = (const f32x2*)&b0[1];
          const f32x2* q1 = (const f32x2*)&b1[1];
          PK_FMA_HI(cur[i][0], ap[0], q0[0]);
          PK_FMA_HI(cur[i][1], ap[0], q0[1]);
          PK_FMA_HI(cur[i][2], ap[0], q1[0]);
          PK_FMA_HI(cur[i][3], ap[0], q1[1]); }
        // cc = 2: a = av.z (ap[1].lo)
        { const f32x2* q0 = (const f32x2*)&b0[2];
          const f32x2* q1 = (const f32x2*)&b1[2];
          PK_FMA_LO(cur[i][0], ap[1], q0[0]);
          PK_FMA_LO(cur[i][1], ap[1], q0[1]);
          PK_FMA_LO(cur[i][2], ap[1], q1[0]);
          PK_FMA_LO(cur[i][3], ap[1], q1[1]); }
        // cc = 3: a = av.w (ap[1].hi)
        { const f32x2* q0 = (const f32x2*)&b0[3];
          const f32x2* q1 = (const f32x2*)&b1[3];
          PK_FMA_HI(cur[i][0], ap[1], q0[0]);
          PK_FMA_HI(cur[i][1], ap[1], q0[1]);
          PK_FMA_HI(cur[i][2], ap[1], q1[0]);
          PK_FMA_HI(cur[i][3], ap[1], q1[1]); }
      }
    }
    aG += 32;
    bG += bStepT;
  }

  // ---- epilogue: per (i,jq), 4 consecutive cols -> one float4 store ----
#pragma unroll
  for (int i = 0; i < 8; ++i) {
    const int m = ty + 16 * i;
    const long b = (long)bm * 128 + m;
#pragma unroll
    for (int jq = 0; jq < 2; ++jq) {
      const int n0 = 4 * tx + 64 * jq;
      const f32x2 e01 = cur[i][2 * jq + 0];
      const f32x2 e23 = cur[i][2 * jq + 1];
      float4 o;
      if (SAMPLE) {
        const int ng = j0 + n0;
        o.x = sample_val(e01.x, bias[ng],     b, ng,     N_total, k0, k1);
        o.y = sample_val(e01.y, bias[ng + 1], b, ng + 1, N_total, k0, k1);
        o.z = sample_val(e23.x, bias[ng + 2], b, ng + 2, N_total, k0, k1);
        o.w = sample_val(e23.y, bias[ng + 3], b, ng + 3, N_total, k0, k1);
        *(float4*)(outp + b * N_total + ng) = o;
      } else {
        o.x = e01.x; o.y = e01.y; o.z = e23.x; o.w = e23.y;
        *(float4*)(outp + b * 128 + n0) = o;   // j0==0, N_total==128
      }
    }
  }
}

// ----------------------------------------------------------------------------
// Fallback (no-workspace path only): 64x128 kernel, SAMPLE over full K with
// in-kernel panel folds (tiles_per_panel=10). Not used when split-K workspace
// is available.
// ----------------------------------------------------------------------------
__global__ __launch_bounds__(256, 5) void gemm_fb(
    const float* __restrict__ A,     // [Mtot, lda]
    const float* __restrict__ Bkm,   // [K, ldb] k-major
    const float* __restrict__ bias,  // [N_total]
    float* __restrict__ out,
    int lda, int ldb, int N_total, int K, int tiles_per_panel, int Mtot,
    uint32_t k0, uint32_t k1)
{
  __shared__ float As[64 * 32];
  __shared__ float Bs[32 * 128];
  const int t  = threadIdx.x;
  const int tx = t & 15;
  const int ty = t >> 4;
  const int w  = t >> 6;
  const int bm = blockIdx.x;
  const int j0 = blockIdx.y << 7;

  const int kb = 0, ke = K;

  float cur[4][8];
  float tot[4][8];
#pragma unroll
  for (int i = 0; i < 4; ++i)
#pragma unroll
    for (int j = 0; j < 8; ++j) { cur[i][j] = 0.0f; tot[i][j] = 0.0f; }

  const long arow = (long)bm * 64 * lda;
  const int t0 = kb >> 5, t1 = ke >> 5;

  const float* aP = As + ty * 32;
  const float* bP = Bs + 4 * tx;

  for (int tki = t0; tki < t1; ++tki) {
    const int kc = tki << 5;
    __syncthreads();
#pragma unroll
    for (int r = 0; r < 2; ++r) {
      int slot = r * 256 + t;
      int m = slot >> 3, c = slot & 7;
      gl2lds16(A + arow + (long)m * lda + kc + 4 * c,
               As + (r * 256 + w * 64) * 4);
    }
#pragma unroll
    for (int r = 0; r < 4; ++r) {
      int slot = r * 256 + t;
      int kk = slot >> 5, nc = slot & 31;
      gl2lds16(Bkm + (long)(kc + kk) * ldb + j0 + 4 * nc,
               Bs + (r * 256 + w * 64) * 4);
    }
    __syncthreads();

#pragma unroll
    for (int c = 0; c < 8; ++c) {
      float4 av[4];
#pragma unroll
      for (int i = 0; i < 4; ++i)
        av[i] = *(const float4*)(aP + i * 16 * 32 + 4 * c);
#pragma unroll
      for (int cc = 0; cc < 4; ++cc) {
        const float* brow = bP + (4 * c + cc) * 128;
        float4 b0 = *(const float4*)(brow);
        float4 b1 = *(const float4*)(brow + 64);
#pragma unroll
        for (int i = 0; i < 4; ++i) {
          const float a = ((const float*)&av[i])[cc];
          cur[i][0] = __fmaf_rn(a, b0.x, cur[i][0]);
          cur[i][1] = __fmaf_rn(a, b0.y, cur[i][1]);
          cur[i][2] = __fmaf_rn(a, b0.z, cur[i][2]);
          cur[i][3] = __fmaf_rn(a, b0.w, cur[i][3]);
          cur[i][4] = __fmaf_rn(a, b1.x, cur[i][4]);
          cur[i][5] = __fmaf_rn(a, b1.y, cur[i][5]);
          cur[i][6] = __fmaf_rn(a, b1.z, cur[i][6]);
          cur[i][7] = __fmaf_rn(a, b1.w, cur[i][7]);
        }
      }
    }

    if (((tki - t0 + 1) % tiles_per_panel == 0) || (tki == t1 - 1)) {
#pragma unroll
      for (int i = 0; i < 4; ++i)
#pragma unroll
        for (int j = 0; j < 8; ++j) { tot[i][j] += cur[i][j]; cur[i][j] = 0.0f; }
    }
  }

#pragma unroll
  for (int i = 0; i < 4; ++i) {
    const int m = ty + 16 * i;
    const long b = (long)bm * 64 + m;
#pragma unroll
    for (int jq = 0; jq < 2; ++jq) {
      const int n0 = 4 * tx + 64 * jq;
      const int ng = j0 + n0;
      float4 o;
      o.x = sample_val(tot[i][4 * jq + 0], bias[ng],     b, ng,     N_total, k0, k1);
      o.y = sample_val(tot[i][4 * jq + 1], bias[ng + 1], b, ng + 1, N_total, k0, k1);
      o.z = sample_val(tot[i][4 * jq + 2], bias[ng + 2], b, ng + 2, N_total, k0, k1);
      o.w = sample_val(tot[i][4 * jq + 3], bias[ng + 3], b, ng + 3, N_total, k0, k1);
      *(float4*)(out + b * N_total + ng) = o;
    }
  }
}

// Fold 4 panel partials in exact order, then bias+sigmoid+sample.
__global__ __launch_bounds__(256) void combine_sample(
    const float* __restrict__ partials,  // [4][Mtot*128]
    const float* __restrict__ bias,      // [128]
    float* __restrict__ out,             // [Mtot*128] binary f32
    int Mtot, uint32_t k0, uint32_t k1)
{
  const long idx = (long)blockIdx.x * 256 + threadIdx.x;
  const long S = (long)Mtot * 128;
  float p0 = partials[idx];
  float p1 = partials[S + idx];
  float p2 = partials[2 * S + idx];
  float p3 = partials[3 * S + idx];
  float tot = ((p0 + p1) + p2) + p3;          // Eigen fold order, exact
  float pre = tot + bias[(int)(idx & 127)];
  float p   = 1.0f / (1.0f + cephes_expf(-pre));
  uint32_t w0, w1;
  threefry2x32(k0, k1, 0u, (uint32_t)idx, w0, w1);
  uint32_t bits = w0 ^ w1;
  float u = __uint_as_float((bits >> 9) | 0x3f800000u) - 1.0f;
  out[idx] = (u < p) ? 1.0f : 0.0f;
}

__global__ void transpose_W(const float* __restrict__ W, float* __restrict__ Wt) {
  __shared__ float tile[32][33];
  int bx = blockIdx.x, by = blockIdx.y;
  int x = threadIdx.x, y = threadIdx.y;
  tile[y][x] = W[(by * 32 + y) * 1024 + bx * 32 + x];
  __syncthreads();
  Wt[(bx * 32 + y) * 128 + by * 32 + x] = tile[x][y];
}

extern "C" void kernel_launch(void* const* d_in, const int* in_sizes, int n_in,
                              void* d_out, int out_size, void* d_ws, size_t ws_size,
                              hipStream_t stream) {
  const float* v0 = (const float*)d_in[0];   // [B,1024]
  const float* W  = (const float*)d_in[1];   // [128,1024]
  const float* bb = (const float*)d_in[2];   // [1024]
  const float* cb = (const float*)d_in[3];   // [128]
  const int B = in_sizes[0] / 1024;          // 32768

  float* out    = (float*)d_out;
  float* out_v  = out;                        // v_given_h   [B,1024]
  float* out_h1 = out + (size_t)B * 1024;     // h_given_v   [B,128]
  float* out_h2 = out_h1 + (size_t)B * 128;   // h_given_v_0 [B,128]

  float* Wt       = (float*)d_ws;                       // [1024,128] k-major for h-GEMM
  float* h_ws     = Wt + 1024 * 128;                    // [B,128]
  float* partials = h_ws + (size_t)B * 128;             // [4][B,128]
  const size_t need = (size_t)(1024 * 128 + (size_t)B * 128 * 5) * 4;
  const bool use_split = ws_size >= need;

  // partitionable keys: seed 42, fold-like split
  uint32_t kt[5][2], kv[5][2], kh[5][2];
  for (uint32_t i = 0; i < 5; ++i) threefry2x32(0u, 42u, 0u, i, kt[i][0], kt[i][1]);
  for (int t = 1; t <= 4; ++t) {
    threefry2x32(kt[t][0], kt[t][1], 0u, 0u, kv[t][0], kv[t][1]);
    threefry2x32(kt[t][0], kt[t][1], 0u, 1u, kh[t][0], kh[t][1]);
  }

  transpose_W<<<dim3(32, 4), dim3(32, 32), 0, stream>>>(W, Wt);

  const int MB = B / 128;    // 256 row-blocks (128-row tiles)

  // h-step: hdst = bernoulli(key, sigmoid(W vin + c)); Bkm = Wt (ldb=128)
  auto h_step = [&](const float* vin, float* hdst, uint32_t hk0, uint32_t hk1) {
    if (use_split) {
      gemm_tile128<false><<<dim3(MB, 1, 4), 256, 0, stream>>>(
          vin, Wt, nullptr, partials, 1024, 128, 128, 1024, B, 0u, 0u);
      combine_sample<<<dim3(B * 128 / 256), 256, 0, stream>>>(
          partials, cb, hdst, B, hk0, hk1);
    } else {
      gemm_fb<<<dim3(B / 64, 1, 1), 256, 0, stream>>>(
          vin, Wt, cb, hdst, 1024, 128, 128, 1024, 10, B, hk0, hk1);
    }
  };

  // h0 = bernoulli(kt[0], sigmoid(W v0 + c))
  h_step(v0, out_h2, kt[0][0], kt[0][1]);

  const float* h = out_h2;
  for (int t = 1; t <= 4; ++t) {
    // v_t = bernoulli(kv[t], sigmoid(W^T h + b)) — K=128 (<320, single panel)
    gemm_tile128<true><<<dim3(MB, 8, 1), 256, 0, stream>>>(
        h, W, bb, out_v, 128, 1024, 1024, 128, B, kv[t][0], kv[t][1]);
    // h_t = bernoulli(kh[t], sigmoid(W v_t + c))
    float* hdst = (t == 4) ? out_h1 : h_ws;
    h_step(out_v, hdst, kh[t][0], kh[t][1]);
    h = hdst;
  }
}